// Round 3
// baseline (187082.715 us; speedup 1.0000x reference)
//
#include <hip/hip_runtime.h>

// ============================================================================
// 2-layer LSTM, persistent kernel, MI355X — round 3.
// Round-2 NaN root-cause: split inline-asm staging (asm load -> later commit)
// let the compiler touch in-flight destination registers -> garbage bits into
// LDS -> bf16 NaN -> propagated. Fixed by making ALL value-carrying loads
// plain C++ (__builtin_nontemporal_load); only write-only stores and the
// barrier spin (load+waitcnt fused in ONE asm) remain inline asm.
//   * h stores: sc0 sc1 (guaranteed LLC residency). h loads: nt (no-allocate,
//     never hits stale L2). Weights plain-cached, L2-resident (no inv fences).
//   * Barrier: relaxed agent atomics + sc01 spin loads + s_sleep (proven live
//     in round 2).
//   * Fused ticks: each staged h0 chunk feeds L0 (Wh0) and L1 (Wx1) MFMAs.
// ============================================================================

typedef unsigned int u32;
typedef unsigned short u16;
typedef __attribute__((ext_vector_type(8))) short bf16x8;
typedef __attribute__((ext_vector_type(4))) float f32x4;

#define MFMA __builtin_amdgcn_mfma_f32_16x16x32_bf16
#define HB (256 * 1024)   // h buffer elems per parity

__device__ __forceinline__ u16 f2bf(float f) {
  u32 u = __float_as_uint(f);
  u += 0x7fffu + ((u >> 16) & 1u);   // RNE (inputs finite)
  return (u16)(u >> 16);
}
__device__ __forceinline__ float sigm(float v) { return 1.f / (1.f + __expf(-v)); }
__device__ __forceinline__ float tanh_(float v) { return 1.f - 2.f / (__expf(2.f * v) + 1.f); }

// ---- write-only / self-contained asm helpers (no liveness hazards) ----
__device__ __forceinline__ u32 ld_u32_sc01(const u32* p) {
  u32 v;
  asm volatile("global_load_dword %0, %1, off sc0 sc1\n\ts_waitcnt vmcnt(0)"
               : "=v"(v) : "v"(p) : "memory");
  return v;
}
__device__ __forceinline__ void st_u32_sc01(u32* p, u32 v) {
  asm volatile("global_store_dword %0, %1, off sc0 sc1" :: "v"(p), "v"(v) : "memory");
}
__device__ __forceinline__ void st_u16_sc01(u16* p, u32 v) {
  asm volatile("global_store_short %0, %1, off sc0 sc1" :: "v"(p), "v"(v) : "memory");
}
__device__ __forceinline__ void st_f32_sc01(float* p, float v) {
  asm volatile("global_store_dword %0, %1, off sc0 sc1" :: "v"(p), "v"(v) : "memory");
}

// ---------------- prologue: f32 -> bf16 weight conversion ----------------
__global__ void __launch_bounds__(256) wconv(
    const float* __restrict__ Wx0, const float* __restrict__ Wh0,
    const float* __restrict__ Wx1, const float* __restrict__ Wh1,
    u16* __restrict__ Wx0b, u16* __restrict__ Wh0b, u16* __restrict__ W1b) {
  const u32 NG0 = 524288u;    // Wh0b groups of 8
  const u32 NG1 = 1048576u;   // W1b  groups
  const u32 NG2 = 32768u;     // Wx0b groups
  u32 g = blockIdx.x * 256u + threadIdx.x;
  const float* s; u16* d;
  if (g < NG0) { s = Wh0 + (size_t)g * 8; d = Wh0b + (size_t)g * 8; }
  else if (g < NG0 + NG1) {
    size_t e = (size_t)(g - NG0) * 8, row = e >> 11, k = e & 2047;
    s = (k < 1024) ? Wx1 + row * 1024 + k : Wh1 + row * 1024 + (k - 1024);
    d = W1b + e;
  } else if (g < NG0 + NG1 + NG2) {
    size_t e = (size_t)(g - NG0 - NG1) * 8;
    s = Wx0 + e; d = Wx0b + e;
  } else return;
  float4 v0 = *(const float4*)s, v1 = *(const float4*)(s + 4);
  bf16x8 r;
  r[0] = (short)f2bf(v0.x); r[1] = (short)f2bf(v0.y);
  r[2] = (short)f2bf(v0.z); r[3] = (short)f2bf(v0.w);
  r[4] = (short)f2bf(v1.x); r[5] = (short)f2bf(v1.y);
  r[6] = (short)f2bf(v1.z); r[7] = (short)f2bf(v1.w);
  *(bf16x8*)d = r;
}

// ---- MFMA tick macros (literal rb/bank so all reg indices are static) ----
#define H0T(rb, bank) do {                                                     \
  _Pragma("unroll")                                                            \
  for (int jj = 0; jj < 2; ++jj) {                                             \
    const int kin_ = (kway + (jj << 2)) << 5;                                  \
    _Pragma("unroll")                                                          \
    for (int mf = 0; mf < 4; ++mf) {                                           \
      bf16x8 a_ = readA(rb, mf, kin_);                                         \
      if (dL0) {                                                               \
        acc0[mf][0] = MFMA(a_, W0[bank][jj][0], acc0[mf][0], 0, 0, 0);         \
        acc0[mf][1] = MFMA(a_, W0[bank][jj][1], acc0[mf][1], 0, 0, 0);         \
      }                                                                        \
      if (dL1) {                                                               \
        acc1[mf][0] = MFMA(a_, W1[bank][jj][0], acc1[mf][0], 0, 0, 0);         \
        acc1[mf][1] = MFMA(a_, W1[bank][jj][1], acc1[mf][1], 0, 0, 0);         \
      }                                                                        \
    }                                                                          \
  }                                                                            \
} while (0)

#define H1T(rb, bank) do {                                                     \
  _Pragma("unroll")                                                            \
  for (int jj = 0; jj < 2; ++jj) {                                             \
    const int kin_ = (kway + (jj << 2)) << 5;                                  \
    _Pragma("unroll")                                                          \
    for (int mf = 0; mf < 4; ++mf) {                                           \
      bf16x8 a_ = readA(rb, mf, kin_);                                         \
      acc1[mf][0] = MFMA(a_, W1[bank][jj][0], acc1[mf][0], 0, 0, 0);           \
      acc1[mf][1] = MFMA(a_, W1[bank][jj][1], acc1[mf][1], 0, 0, 0);           \
    }                                                                          \
  }                                                                            \
} while (0)

__global__ void __launch_bounds__(512, 2)
lstm_persist(const float* __restrict__ x,
             const float* __restrict__ b0, const float* __restrict__ b1,
             const float* __restrict__ fcW, const float* __restrict__ fcb,
             const u16* __restrict__ Wx0b, const u16* __restrict__ Wh0b,
             const u16* __restrict__ W1b,
             u16* __restrict__ h0b, u16* __restrict__ h1b,
             float* __restrict__ h1f, u32* __restrict__ bar,
             float* __restrict__ out)
{
  const int tid = threadIdx.x, blk = blockIdx.x;
  const int lane = tid & 63, w = tid >> 6;
  const int s = w >> 2;        // n32 slice 0/1
  const int kway = w & 3;      // k-interleave lane
  const int m0 = (blk >> 6) << 6;   // batch tile base
  const int u0 = (blk & 63) << 4;   // hidden-unit base

  __shared__ short Abuf[2][64 * 256];   // 2 x 32KB A chunks
  __shared__ float gA[64][68];          // k-reduce region A
  __shared__ float gB[64][68];          // k-reduce region B
  __shared__ float cbuf[2][64][16];     // persistent c state

  for (int i = tid; i < 2 * 64 * 16; i += 512) ((float*)cbuf)[i] = 0.f;

  const int i15 = lane & 15, kq = lane >> 4;

  int rowf[2];
#pragma unroll
  for (int f = 0; f < 2; ++f)
    rowf[f] = ((f << 1) + (i15 >> 3)) * 1024 + u0 + s * 8 + (i15 & 7);

  // weight fragment base pointers (streamed from L2 each phase, plain cached)
  const u16* w0base[2]; const u16* w1base[2];
#pragma unroll
  for (int f = 0; f < 2; ++f) {
    w0base[f] = Wh0b + (size_t)rowf[f] * 1024 + (kway << 5) + (kq << 3);
    w1base[f] = W1b  + (size_t)rowf[f] * 2048 + (kway << 5) + (kq << 3);
  }

  bf16x8 X0[2];   // Wx0 frags (loop-invariant, kway<2 only)
  if (kway < 2) {
#pragma unroll
    for (int f = 0; f < 2; ++f)
      X0[f] = *(const bf16x8*)(Wx0b + (size_t)rowf[f] * 64 + (kway << 5) + (kq << 3));
  }

  float bias0[2], bias1[2];
#pragma unroll
  for (int f = 0; f < 2; ++f) {
    bias0[f] = (kway == 0) ? b0[rowf[f]] : 0.f;
    bias1[f] = (kway == 0) ? b1[rowf[f]] : 0.f;
  }

  // staging address precompute
  int grow[4], ldsoff[4];
#pragma unroll
  for (int cc = 0; cc < 4; ++cc) {
    int call = (w << 2) | cc;
    int row = (call << 1) | (lane >> 5);
    int c = lane & 31;
    grow[cc]   = ((m0 + row) << 10) + (c << 3);
    ldsoff[cc] = (row << 8) + ((c ^ (row & 7)) << 3);
  }

  bf16x8 v[4];   // staging values — PLAIN C++ (compiler-managed liveness)

  auto stage_ld = [&](const u16* src, int kbase) {
#pragma unroll
    for (int cc = 0; cc < 4; ++cc)
      v[cc] = __builtin_nontemporal_load((const bf16x8*)(src + grow[cc] + kbase));
  };
  auto stage_st = [&](int bsel) {
#pragma unroll
    for (int cc = 0; cc < 4; ++cc)
      *(bf16x8*)&Abuf[bsel][ldsoff[cc]] = v[cc];
  };

  auto stage_x = [&](int t) {   // x tile 64x64 f32 -> bf16 into Abuf[0]
    int row = tid >> 3, c = tid & 7;
    const float* g = x + ((size_t)(m0 + row) * 512 + t) * 64 + (c << 3);
    float4 v0 = *(const float4*)g;
    float4 v1 = *(const float4*)(g + 4);
    bf16x8 r;
    r[0] = (short)f2bf(v0.x); r[1] = (short)f2bf(v0.y);
    r[2] = (short)f2bf(v0.z); r[3] = (short)f2bf(v0.w);
    r[4] = (short)f2bf(v1.x); r[5] = (short)f2bf(v1.y);
    r[6] = (short)f2bf(v1.z); r[7] = (short)f2bf(v1.w);
    *(bf16x8*)&Abuf[0][(row << 8) + ((c ^ (row & 7)) << 3)] = r;
  };

  auto readA = [&](int bsel, int mf, int kin) -> bf16x8 {
    int row = (mf << 4) | i15;
    int c = ((kin >> 3) + kq) ^ (row & 7);
    return *(const bf16x8*)&Abuf[bsel][(row << 8) + (c << 3)];
  };

  bf16x8 W0[2][2][2], W1[2][2][2];   // [bank][jj][f] streamed weights
  auto ldW0p = [&](int bank, int c) {
#pragma unroll
    for (int jj = 0; jj < 2; ++jj)
#pragma unroll
      for (int f = 0; f < 2; ++f)
        W0[bank][jj][f] = *(const bf16x8*)(w0base[f] + (2 * c + jj) * 128);
  };
  auto ldW1p = [&](int bank, int c) {
#pragma unroll
    for (int jj = 0; jj < 2; ++jj)
#pragma unroll
      for (int f = 0; f < 2; ++f)
        W1[bank][jj][f] = *(const bf16x8*)(w1base[f] + (2 * c + jj) * 128);
  };

  f32x4 acc0[4][2], acc1[4][2];
  auto acc_init = [&](f32x4 (&acc)[4][2], const float* bias) {
#pragma unroll
    for (int mf = 0; mf < 4; ++mf)
#pragma unroll
      for (int f = 0; f < 2; ++f) {
        acc[mf][f][0] = bias[f]; acc[mf][f][1] = bias[f];
        acc[mf][f][2] = bias[f]; acc[mf][f][3] = bias[f];
      }
  };

  auto reduce2 = [&](f32x4 (&acc)[4][2]) {
    if (kway < 2) {
      float (*g)[68] = kway ? gB : gA;
#pragma unroll
      for (int mf = 0; mf < 4; ++mf)
#pragma unroll
        for (int f = 0; f < 2; ++f)
#pragma unroll
          for (int r = 0; r < 4; ++r)
            g[(mf << 4) + (kq << 2) + r][(s << 5) + (f << 4) + i15] = acc[mf][f][r];
    }
    __syncthreads();
    if (kway >= 2) {
      float (*g)[68] = (kway == 3) ? gB : gA;
#pragma unroll
      for (int mf = 0; mf < 4; ++mf)
#pragma unroll
        for (int f = 0; f < 2; ++f)
#pragma unroll
          for (int r = 0; r < 4; ++r)
            g[(mf << 4) + (kq << 2) + r][(s << 5) + (f << 4) + i15] += acc[mf][f][r];
    }
    __syncthreads();
  };

  auto ew = [&](int L, u16* hdst, bool wf32) {
#pragma unroll
    for (int e0 = 0; e0 < 2; ++e0) {
      int e = tid + (e0 << 9);
      int row = e >> 4, un = e & 15;
      int cb = ((un >> 3) << 5) | (un & 7);
      float gi = gA[row][cb]      + gB[row][cb];
      float gf = gA[row][cb + 8]  + gB[row][cb + 8];
      float gg = gA[row][cb + 16] + gB[row][cb + 16];
      float go = gA[row][cb + 24] + gB[row][cb + 24];
      float ii = sigm(gi), ff = sigm(gf), g2 = tanh_(gg), oo = sigm(go);
      float c = ff * cbuf[L][row][un] + ii * g2;
      cbuf[L][row][un] = c;
      float h = oo * tanh_(c);
      size_t idx = ((size_t)(m0 + row) << 10) + u0 + un;
      st_u16_sc01(hdst + idx, (u32)f2bf(h));
      if (wf32) st_f32_sc01(h1f + idx, h);
    }
  };

  // ---------------- phase loop: phase t = { L0(t), L1(t-1) } ----------------
#pragma unroll 1
  for (int t = 0; t <= 512; ++t) {
    const u16* h0rd = h0b + ((t + 1) & 1) * HB;
    u16* h0wr = h0b + (t & 1) * HB;
    const u16* h1rd = h1b + (t & 1) * HB;
    u16* h1wr = h1b + ((t + 1) & 1) * HB;
    const bool dL0 = (t < 512), dL1 = (t >= 1);

    if (dL0) acc_init(acc0, bias0);
    if (dL1) acc_init(acc1, bias1);

    if (dL0) stage_x(t);
    ldW0p(0, 0); ldW1p(0, 0);
    stage_ld(h0rd, 0);
    __syncthreads();                    // x tile published
    if (dL0 && kway < 2) {              // x-tick: K=64 of layer0
      const int kin = kway << 5;
#pragma unroll
      for (int mf = 0; mf < 4; ++mf) {
        bf16x8 a = readA(0, mf, kin);
        acc0[mf][0] = MFMA(a, X0[0], acc0[mf][0], 0, 0, 0);
        acc0[mf][1] = MFMA(a, X0[1], acc0[mf][1], 0, 0, 0);
      }
    }
    stage_st(1);                        // h0 chunk0 -> buf1
    __syncthreads();

    // unified ticks: chunk c (h0 c<4, h1 c>=4), W bank alternates
    stage_ld(h0rd, 256); ldW0p(1, 1); ldW1p(1, 1); H0T(1, 0); stage_st(0); __syncthreads();
    stage_ld(h0rd, 512); ldW0p(0, 2); ldW1p(0, 2); H0T(0, 1); stage_st(1); __syncthreads();
    stage_ld(h0rd, 768); ldW0p(1, 3); ldW1p(1, 3); H0T(1, 0); stage_st(0); __syncthreads();
    if (dL1) stage_ld(h1rd, 0);
    ldW1p(0, 4); H0T(0, 1);
    if (dL1) stage_st(1);
    __syncthreads();
    if (dL1) {
      stage_ld(h1rd, 256); ldW1p(1, 5); H1T(1, 0); stage_st(0); __syncthreads();
      stage_ld(h1rd, 512); ldW1p(0, 6); H1T(0, 1); stage_st(1); __syncthreads();
      stage_ld(h1rd, 768); ldW1p(1, 7); H1T(1, 0); stage_st(0); __syncthreads();
      H1T(0, 1); __syncthreads();
    }

    if (dL0) { reduce2(acc0); ew(0, h0wr, false); }
    if (dL1) { __syncthreads(); reduce2(acc1); ew(1, h1wr, t == 512); }

    // ---- grid barrier: relaxed agent atomics + sc01 spins (proven live) ----
    __syncthreads();                    // drains vmcnt -> h stores at LLC
    if (tid == 0) {
      const int g = blk & 7;
      u32* gc   = bar + g * 32;
      u32* root = bar + 256;
      u32* gen  = bar + 288 + g * 32;
      const u32 p1 = (u32)(t + 1);
      __hip_atomic_fetch_add(gc, 1u, __ATOMIC_RELAXED, __HIP_MEMORY_SCOPE_AGENT);
      if (blk < 8) {
        while (ld_u32_sc01(gc) < 32u * p1) __builtin_amdgcn_s_sleep(4);
        __hip_atomic_fetch_add(root, 1u, __ATOMIC_RELAXED, __HIP_MEMORY_SCOPE_AGENT);
        while (ld_u32_sc01(root) < 8u * p1) __builtin_amdgcn_s_sleep(2);
        st_u32_sc01(gen, p1);
      } else {
        while (ld_u32_sc01(gen) < p1) __builtin_amdgcn_s_sleep(4);
      }
    }
    __syncthreads();
  }

  // ---------------- fc epilogue ----------------
  if (blk < 32) {
    const int row = (blk << 3) | w;
    const float* hrow = h1f + ((size_t)row << 10);
#pragma unroll 1
    for (int o = 0; o < 12; ++o) {
      const float* wrow = fcW + o * 1024;
      float p = 0.f;
#pragma unroll
      for (int j = 0; j < 16; ++j) {
        int k = (j << 6) | lane;
        p += __builtin_nontemporal_load(hrow + k) * wrow[k];
      }
#pragma unroll
      for (int off = 32; off > 0; off >>= 1) p += __shfl_down(p, off, 64);
      if (lane == 0) out[row * 12 + o] = p + fcb[o];
    }
  }
}

extern "C" void kernel_launch(void* const* d_in, const int* in_sizes, int n_in,
                              void* d_out, int out_size, void* d_ws, size_t ws_size,
                              hipStream_t stream) {
  (void)in_sizes; (void)n_in; (void)out_size; (void)ws_size;
  const float* x   = (const float*)d_in[0];
  const float* Wx0 = (const float*)d_in[1];
  const float* Wh0 = (const float*)d_in[2];
  const float* b0  = (const float*)d_in[3];
  const float* Wx1 = (const float*)d_in[4];
  const float* Wh1 = (const float*)d_in[5];
  const float* b1  = (const float*)d_in[6];
  const float* fcW = (const float*)d_in[7];
  const float* fcb = (const float*)d_in[8];

  char* ws = (char*)d_ws;
  u16* Wh0b  = (u16*)ws;                          //  8 MiB
  u16* W1b   = (u16*)(ws + (8u << 20));           // 16 MiB
  u16* Wx0b  = (u16*)(ws + (24u << 20));          // 512 KiB
  u16* h0b   = (u16*)(ws + (25u << 20));          // 2 x 512 KiB
  u16* h1b   = (u16*)(ws + (26u << 20));          // 2 x 512 KiB
  float* h1f = (float*)(ws + (27u << 20));        // 1 MiB
  u32* bar   = (u32*)(ws + (28u << 20));          // counters

  hipMemsetAsync(ws + (25u << 20) + (1 << 19), 0, 1 << 19, stream);  // h0b[1]
  hipMemsetAsync(ws + (26u << 20) + (1 << 19), 0, 1 << 19, stream);  // h1b[1]
  hipMemsetAsync(bar, 0, 4096, stream);

  wconv<<<6272, 256, 0, stream>>>(Wx0, Wh0, Wx1, Wh1, Wx0b, Wh0b, W1b);
  lstm_persist<<<256, 512, 0, stream>>>(x, b0, b1, fcW, fcb,
                                        Wx0b, Wh0b, W1b,
                                        h0b, h1b, h1f, bar, (float*)d_out);
}